// Round 5
// baseline (1009.549 us; speedup 1.0000x reference)
//
#include <hip/hip_runtime.h>
#include <hip/hip_bf16.h>
#include <math.h>

#define Bn   384
#define INn  512
#define OUTn 384

typedef __bf16 bf16x8 __attribute__((ext_vector_type(8)));
typedef __bf16 bf16x4 __attribute__((ext_vector_type(4)));
typedef float  f32x4  __attribute__((ext_vector_type(4)));

// Device-global scratch (no assumption about ws_size).
// g_Wf: W in MFMA-fragment order: f = ((((o>>4)*16 + (i>>5))*4 + ((i>>3)&3))*16 + (o&15))*8 + (i&7)
//       -> a wave's fragment load is lane*16B contiguous (1KB/instr).
__device__ __bf16 g_Wf [OUTn * INn];
__device__ float  g_Wt [INn * OUTn];                 // W transposed fp32, [i][o]
__device__ float  g_spt[INn * OUTn];                 // softplus(sw) transposed, [i][o]
__device__ float  g_d  [Bn * OUTn];                  // s1+s3 diagonal vector
__device__ float  g_t  [Bn * INn];                   // diag(sigma_b), fp32
// U2[b][i>>2][p][i&3] bf16. A passA block's region (16 i-groups x 384 p x 4)
// is one CONTIGUOUS 48KB span -> staged epilogue streams it with 1KB/instr.
__device__ __bf16 g_U  [(size_t)Bn * OUTn * INn];

// ---------------------------------------------------------------------------
// prep: g_Wf (fragment-ordered bf16 W); g_Wt/g_spt fp32 transposes for k2
// ---------------------------------------------------------------------------
__global__ __launch_bounds__(256) void prep_kernel(const float* __restrict__ W,
                                                   const float* __restrict__ sw) {
    int idx = blockIdx.x * 256 + threadIdx.x;
    if (idx < OUTn * INn) {
        const int o = idx >> 9, i = idx & 511;   // idx = o*INn + i
        float w = W[idx];
        const int f = ((((o >> 4) * 16 + (i >> 5)) * 4 + ((i >> 3) & 3)) * 16 + (o & 15)) * 8 + (i & 7);
        g_Wf[f] = (__bf16)w;
        g_Wt[i * OUTn + o] = w;
        float x = sw[idx];
        g_spt[i * OUTn + o] = (x > 20.f) ? x : log1pf(expf(x));
    }
}

// ---------------------------------------------------------------------------
// passA: U2[b][i>>2][p][i&3] = sum_j sigma[b,i,j] * W[p,j]   (bf16 out)
// grid (8 i-tiles of 64, 384 b), 512 thr = 8 waves.
// 2-phase pipelined K (4 chunks of 128 j, double-buffered LDS) exactly as
// round 4. EPILOGUE CHANGED: D-fragments -> 48KB LDS image in global layout,
// then 6 x (64 lanes x 16B contiguous) linear stores -> write amp 1.
// Diagonal extracted fp32-exact during staging -> g_t.
// MFMA 16x16x32: A frag [row=l15][k=quad*8+j]; D [row=quad*4+r][col=l15].
// ---------------------------------------------------------------------------
__global__ __launch_bounds__(512, 4) void passA_kernel(const float* __restrict__ sigma) {
    __shared__ __align__(16) unsigned char smem[49152];   // As (34.8KB) then Uo (48KB)
    typedef __bf16 AsT[64][136];
    AsT* As = (AsT*)smem;                                 // As[buf][row][col]

    const int it   = blockIdx.x;    // 0..7
    const int b    = blockIdx.y;    // 0..383
    const int tid  = threadIdx.x;
    const int wave = tid >> 6, lane = tid & 63;
    const int quad = lane >> 4, l15 = lane & 15;
    const int i0     = it * 64;
    const int p_base = wave * 48;   // 8 waves x 48 = 384 p
    const int srow   = tid >> 3;        // staging row 0..63
    const int scol   = (tid & 7) * 16;  // staging col (f32 elems) 0..112

    const float* sigb   = sigma + (size_t)b * (INn * INn);
    const float* srcRow = sigb + (size_t)(i0 + srow) * INn + scol;

    float4 r0, r1, r2, r3;   // staged chunk (16 f32/thread)

    auto LOAD = [&](int c) {
        const float4* p = (const float4*)(srcRow + c * 128);
        r0 = p[0]; r1 = p[1]; r2 = p[2]; r3 = p[3];
    };
    auto STORE = [&](int c, int buf) {
        const int ig   = i0 + srow;
        const int base = c * 128 + scol;
        if (ig >= base && ig < base + 16) {          // fp32-exact diagonal
            const int j = ig - base;
            float4 v = (j < 4) ? r0 : (j < 8) ? r1 : (j < 12) ? r2 : r3;
            const int e = j & 3;
            float dv = (e == 0) ? v.x : (e == 1) ? v.y : (e == 2) ? v.z : v.w;
            g_t[b * INn + ig] = dv;
        }
        bf16x8 t0, t1;
        t0[0]=(__bf16)r0.x; t0[1]=(__bf16)r0.y; t0[2]=(__bf16)r0.z; t0[3]=(__bf16)r0.w;
        t0[4]=(__bf16)r1.x; t0[5]=(__bf16)r1.y; t0[6]=(__bf16)r1.z; t0[7]=(__bf16)r1.w;
        t1[0]=(__bf16)r2.x; t1[1]=(__bf16)r2.y; t1[2]=(__bf16)r2.z; t1[3]=(__bf16)r2.w;
        t1[4]=(__bf16)r3.x; t1[5]=(__bf16)r3.y; t1[6]=(__bf16)r3.z; t1[7]=(__bf16)r3.w;
        *(bf16x8*)&As[buf][srow][scol]     = t0;
        *(bf16x8*)&As[buf][srow][scol + 8] = t1;
    };

    f32x4 acc[4][3];
#pragma unroll
    for (int mi = 0; mi < 4; ++mi)
#pragma unroll
        for (int nf = 0; nf < 3; ++nf) acc[mi][nf] = (f32x4){0.f, 0.f, 0.f, 0.f};

    auto COMPUTE = [&](int buf, int kc0) {
#pragma unroll
        for (int kcl = 0; kcl < 128; kcl += 32) {
            bf16x8 afr[4];
#pragma unroll
            for (int mi = 0; mi < 4; ++mi)
                afr[mi] = *(const bf16x8*)&As[buf][mi * 16 + l15][kcl + quad * 8];
#pragma unroll
            for (int nf = 0; nf < 3; ++nf) {
                const int ot   = wave * 3 + nf;
                const int kc32 = (kc0 + kcl) >> 5;
                const __bf16* bp = g_Wf + ((((size_t)(ot * 16 + kc32) * 4 + quad) * 16 + l15) << 3);
                bf16x8 bfr = *(const bf16x8*)bp;
#pragma unroll
                for (int mi = 0; mi < 4; ++mi)
                    acc[mi][nf] = __builtin_amdgcn_mfma_f32_16x16x32_bf16(afr[mi], bfr, acc[mi][nf], 0, 0, 0);
            }
        }
    };

    // ---- pipelined K loop ----
    LOAD(0); STORE(0, 0); LOAD(1);
    __syncthreads();
    COMPUTE(0, 0);
    __syncthreads(); STORE(1, 1); LOAD(2); __syncthreads();
    COMPUTE(1, 128);
    __syncthreads(); STORE(2, 0); LOAD(3); __syncthreads();
    COMPUTE(0, 256);
    __syncthreads(); STORE(3, 1); __syncthreads();
    COMPUTE(1, 384);

    // ---- staged epilogue: frags -> LDS (global layout) -> linear 1KB stores ----
    __syncthreads();                         // all As reads done; reuse smem
    __bf16* Uo = (__bf16*)smem;              // 16 i-groups x 384 p x 4 = 48KB
#pragma unroll
    for (int mi = 0; mi < 4; ++mi) {
        const int i4l = mi * 4 + quad;       // local i-group 0..15
#pragma unroll
        for (int nf = 0; nf < 3; ++nf) {
            const int p = p_base + nf * 16 + l15;
            bf16x4 v;
            v[0] = (__bf16)acc[mi][nf][0];
            v[1] = (__bf16)acc[mi][nf][1];
            v[2] = (__bf16)acc[mi][nf][2];
            v[3] = (__bf16)acc[mi][nf][3];
            *(bf16x4*)&Uo[(i4l * OUTn + p) * 4] = v;
        }
    }
    __syncthreads();
    {   // block's U region is contiguous: start elem = (b*128 + it*16)*1536
        char* dst = (char*)(g_U + (size_t)(b * 128 + it * 16) * 1536);
#pragma unroll
        for (int r = 0; r < 6; ++r) {
            const int L = r * 8192 + tid * 16;   // byte offset, 6*8192 = 49152
            *(bf16x8*)(dst + L) = *(const bf16x8*)(smem + L);
        }
    }
}

// ---------------------------------------------------------------------------
// k2: mu_f[b,o] = mu[b,:]·W[o,:] + bias[o]
//     d[b,o]   = sum_i (diag_sigma[b,i] + mu[b,i]^2) * sp[o,i] + (o==b)*sbias[o]
// ---------------------------------------------------------------------------
__global__ __launch_bounds__(384) void k2_kernel(const float* __restrict__ mu,
                                                 const float* __restrict__ bias,
                                                 const float* __restrict__ sbias,
                                                 float* __restrict__ out_muf) {
    const int b = blockIdx.x;
    const int t = threadIdx.x;   // = o
    __shared__ __align__(16) float muL[INn];
    __shared__ __align__(16) float tL[INn];
    for (int i = t; i < INn; i += 384) {
        float m = mu[b * INn + i];
        muL[i] = m;
        tL[i] = g_t[b * INn + i] + m * m;
    }
    __syncthreads();
    float mf = 0.f, dd = 0.f;
#pragma unroll 8
    for (int i = 0; i < INn; ++i) {
        mf += g_Wt[i * OUTn + t] * muL[i];
        dd += g_spt[i * OUTn + t] * tL[i];
    }
    out_muf[b * OUTn + t] = mf + bias[t];
    g_d[b * OUTn + t] = dd + (t == b ? sbias[t] : 0.f);
}

// ---------------------------------------------------------------------------
// passB: out[b,o,p0+p] = sum_i W[o,i] * U[b,p0+p,i]  (+ d[b,o] if o==p)
// grid (6 p-tiles of 64, 384 b), 512 thr = 8 waves. Barrier-free main loop
// (round-4, verified). EPILOGUE CHANGED: fp32 out staged through 48KB LDS in
// two o-halves, streamed as 16B/lane row-contiguous stores -> write amp 1.
// ---------------------------------------------------------------------------
__global__ __launch_bounds__(512, 4) void passB_kernel(float* __restrict__ outS) {
    __shared__ __align__(16) float Os[192 * 64];   // 48KB: 192 o-rows x 64 p

    const int ptile = blockIdx.x;   // 0..5
    const int b     = blockIdx.y;   // 0..383
    const int tid   = threadIdx.x;
    const int wave  = tid >> 6, lane = tid & 63;
    const int quad  = lane >> 4, l15 = lane & 15;
    const int p0     = ptile * 64;
    const int o_base = wave * 48;   // 8 waves x 48 = 384 o

    const __bf16* Ub = g_U + (size_t)b * (OUTn * INn);

    f32x4 acc[3][4];
#pragma unroll
    for (int mi = 0; mi < 3; ++mi)
#pragma unroll
        for (int nf = 0; nf < 4; ++nf) acc[mi][nf] = (f32x4){0.f, 0.f, 0.f, 0.f};

    for (int kc = 0; kc < INn; kc += 32) {
        bf16x8 afr[3];
#pragma unroll
        for (int mi = 0; mi < 3; ++mi) {
            const int ot = wave * 3 + mi;
            const __bf16* ap = g_Wf + ((((size_t)(ot * 16 + (kc >> 5)) * 4 + quad) * 16 + l15) << 3);
            afr[mi] = *(const bf16x8*)ap;
        }
        const int i4 = (kc >> 2) + quad * 2;
#pragma unroll
        for (int nf = 0; nf < 4; ++nf) {
            const int p = p0 + nf * 16 + l15;
            bf16x4 lo = *(const bf16x4*)(Ub + ((size_t)i4 * OUTn + p) * 4);
            bf16x4 hi = *(const bf16x4*)(Ub + ((size_t)(i4 + 1) * OUTn + p) * 4);
            bf16x8 bfr;
            bfr[0]=lo[0]; bfr[1]=lo[1]; bfr[2]=lo[2]; bfr[3]=lo[3];
            bfr[4]=hi[0]; bfr[5]=hi[1]; bfr[6]=hi[2]; bfr[7]=hi[3];
#pragma unroll
            for (int mi = 0; mi < 3; ++mi)
                acc[mi][nf] = __builtin_amdgcn_mfma_f32_16x16x32_bf16(afr[mi], bfr, acc[mi][nf], 0, 0, 0);
        }
    }

    // ---- staged epilogue: two o-halves of 192 rows through 48KB LDS ----
    float* outb = outS + (size_t)b * (OUTn * OUTn);
    const int halfId = wave >> 2;   // waves 0-3 own o 0..191, waves 4-7 own 192..383
#pragma unroll
    for (int h = 0; h < 2; ++h) {
        if (h) __syncthreads();     // protect Os from previous half's copy
        if (halfId == h) {
#pragma unroll
            for (int mi = 0; mi < 3; ++mi) {
                const int o_loc = (wave & 3) * 48 + mi * 16 + quad * 4;
#pragma unroll
                for (int nf = 0; nf < 4; ++nf) {
                    const int p_loc = nf * 16 + l15;
                    const int p = p0 + p_loc;
#pragma unroll
                    for (int r = 0; r < 4; ++r) {
                        const int o = h * 192 + o_loc + r;
                        float v = acc[mi][nf][r];
                        if (o == p) v += g_d[b * OUTn + o];
                        Os[(o_loc + r) * 64 + p_loc] = v;
                    }
                }
            }
        }
        __syncthreads();
        // copy 48KB: each instr = 16 lanes x 16B covering one 256B o-row
#pragma unroll
        for (int r = 0; r < 6; ++r) {
            const int L     = r * 8192 + tid * 16;   // byte offset in Os
            const int o_loc = L >> 8;                // 256B per o-row
            const int pb    = L & 255;
            *(f32x4*)((char*)outb + (size_t)(h * 192 + o_loc) * (OUTn * 4) + p0 * 4 + pb) =
                *(const f32x4*)((const char*)Os + L);
        }
    }
}

// ---------------------------------------------------------------------------
extern "C" void kernel_launch(void* const* d_in, const int* in_sizes, int n_in,
                              void* d_out, int out_size, void* d_ws, size_t ws_size,
                              hipStream_t stream) {
    const float* mu    = (const float*)d_in[0];
    const float* sigma = (const float*)d_in[1];
    const float* W     = (const float*)d_in[2];
    const float* bias  = (const float*)d_in[3];
    const float* sw    = (const float*)d_in[4];
    const float* sbias = (const float*)d_in[5];

    float* out     = (float*)d_out;
    float* out_muf = out;                  // [384, 384]
    float* out_sig = out + Bn * OUTn;      // [384, 384, 384]

    prep_kernel<<<(OUTn * INn + 255) / 256, 256, 0, stream>>>(W, sw);
    passA_kernel<<<dim3(8, Bn), 512, 0, stream>>>(sigma);                    // g_U, g_t
    k2_kernel<<<Bn, 384, 0, stream>>>(mu, bias, sbias, out_muf);             // g_d
    passB_kernel<<<dim3(6, Bn), 512, 0, stream>>>(out_sig);
}

// Round 6
// 841.507 us; speedup vs baseline: 1.1997x; 1.1997x over previous
//
#include <hip/hip_runtime.h>
#include <hip/hip_bf16.h>
#include <math.h>

#define Bn   384
#define INn  512
#define OUTn 384

typedef __bf16 bf16x8 __attribute__((ext_vector_type(8)));
typedef __bf16 bf16x4 __attribute__((ext_vector_type(4)));
typedef float  f32x4  __attribute__((ext_vector_type(4)));

// Device-global scratch (no assumption about ws_size).
// g_Wf: W in MFMA-fragment order: f = ((((o>>4)*16 + (i>>5))*4 + ((i>>3)&3))*16 + (o&15))*8 + (i&7)
//       -> a wave's fragment load is lane*16B contiguous (1KB/instr).
__device__ __bf16 g_Wf [OUTn * INn];
__device__ float  g_Wt [INn * OUTn];                 // W transposed fp32, [i][o]
__device__ float  g_spt[INn * OUTn];                 // softplus(sw) transposed, [i][o]
__device__ float  g_d  [Bn * OUTn];                  // s1+s3 diagonal vector
__device__ float  g_t  [Bn * INn];                   // diag(sigma_b), fp32
// U2[b][i>>2][p][i&3] bf16. A passA block's region (16 i-groups x 384 p x 4)
// is one CONTIGUOUS 48KB span.
__device__ __bf16 g_U  [(size_t)Bn * OUTn * INn];

// ---------------------------------------------------------------------------
// prep: g_Wf (fragment-ordered bf16 W); g_Wt/g_spt fp32 transposes for k2
// ---------------------------------------------------------------------------
__global__ __launch_bounds__(256) void prep_kernel(const float* __restrict__ W,
                                                   const float* __restrict__ sw) {
    int idx = blockIdx.x * 256 + threadIdx.x;
    if (idx < OUTn * INn) {
        const int o = idx >> 9, i = idx & 511;   // idx = o*INn + i
        float w = W[idx];
        const int f = ((((o >> 4) * 16 + (i >> 5)) * 4 + ((i >> 3) & 3)) * 16 + (o & 15)) * 8 + (i & 7);
        g_Wf[f] = (__bf16)w;
        g_Wt[i * OUTn + o] = w;
        float x = sw[idx];
        g_spt[i * OUTn + o] = (x > 20.f) ? x : log1pf(expf(x));
    }
}

// ---------------------------------------------------------------------------
// passA: U2[b][i>>2][p][i&3] = sum_j sigma[b,i,j] * W[p,j]   (bf16 out)
// grid (8 i-tiles of 64, 384 b), 512 thr = 8 waves.
// K-loop: 8 chunks of 64 j, sigma staged fp32 DIRECTLY into LDS via
// global_load_lds (zero VGPRs held -> no scratch spills). Double-buffered;
// T3-minimum schedule: STAGE(c+1) -> COMPUTE(c) -> __syncthreads().
// LDS is linear (gload_lds requirement); bank-conflict-free via XOR swizzle
// applied on the GLOBAL source address and the ds_read address (rule 21):
//   LDS[r][u] (16B units u=0..15) holds global unit (u ^ (r&15)).
// f32->bf16 conversion happens at fragment-read time.
// Epilogue identical to round 5 (LDS-staged linear 1KB stores).
// MFMA 16x16x32: A frag [row=l15][k=quad*8+j]; D [row=quad*4+r][col=l15].
// ---------------------------------------------------------------------------
__global__ __launch_bounds__(512, 4) void passA_kernel(const float* __restrict__ sigma) {
    __shared__ __align__(16) unsigned char smem[49152];   // As 2x16KB, epi 48KB
    typedef float AsT[64][64];
    AsT* As = (AsT*)smem;                                 // As[buf][row][col f32]

    const int it   = blockIdx.x;    // 0..7
    const int b    = blockIdx.y;    // 0..383
    const int tid  = threadIdx.x;
    const int wave = tid >> 6, lane = tid & 63;
    const int quad = lane >> 4, l15 = lane & 15;
    const int i0     = it * 64;
    const int p_base = wave * 48;   // 8 waves x 48 = 384 p

    const float* sigb = sigma + (size_t)b * (INn * INn);

    // ---- async stage: chunk c (64 rows x 64 f32) -> As[buf], swizzled src ----
    auto STAGE = [&](int c, int buf) {
#pragma unroll
        for (int g = 0; g < 2; ++g) {
            const int rt  = wave * 8 + g * 4 + (lane >> 4);     // row 0..63
            const int g16 = (lane & 15) ^ (rt & 15);            // swizzled unit
            const float* src = sigb + (size_t)(i0 + rt) * INn + c * 64 + g16 * 4;
            float* dst = &As[buf][wave * 8 + g * 4][0];         // wave-uniform
            __builtin_amdgcn_global_load_lds(
                (const __attribute__((address_space(1))) void*)src,
                (__attribute__((address_space(3))) void*)dst, 16, 0, 0);
        }
    };

    f32x4 acc[4][3];
#pragma unroll
    for (int mi = 0; mi < 4; ++mi)
#pragma unroll
        for (int nf = 0; nf < 3; ++nf) acc[mi][nf] = (f32x4){0.f, 0.f, 0.f, 0.f};

    auto COMPUTE = [&](int buf, int c) {
#pragma unroll
        for (int ks = 0; ks < 2; ++ks) {
            const int kc32 = c * 2 + ks;
            bf16x8 bfr[3];
#pragma unroll
            for (int nf = 0; nf < 3; ++nf) {
                const int ot = wave * 3 + nf;
                bfr[nf] = *(const bf16x8*)(g_Wf +
                    ((((size_t)(ot * 16 + kc32) * 4 + quad) * 16 + l15) << 3));
            }
#pragma unroll
            for (int mi = 0; mi < 4; ++mi) {
                const int rt = mi * 16 + l15;                 // rt&15 == l15
                const int e  = ks * 8 + quad * 2;
                f32x4 x0 = *(const f32x4*)&As[buf][rt][(e ^ l15) * 4];
                f32x4 x1 = *(const f32x4*)&As[buf][rt][((e + 1) ^ l15) * 4];
                bf16x8 a;
                a[0]=(__bf16)x0[0]; a[1]=(__bf16)x0[1]; a[2]=(__bf16)x0[2]; a[3]=(__bf16)x0[3];
                a[4]=(__bf16)x1[0]; a[5]=(__bf16)x1[1]; a[6]=(__bf16)x1[2]; a[7]=(__bf16)x1[3];
#pragma unroll
                for (int nf = 0; nf < 3; ++nf)
                    acc[mi][nf] = __builtin_amdgcn_mfma_f32_16x16x32_bf16(a, bfr[nf], acc[mi][nf], 0, 0, 0);
            }
        }
    };

    // ---- pipelined K loop (T3-minimum) ----
    STAGE(0, 0);
    __syncthreads();
    int buf = 0;
#pragma unroll
    for (int c = 0; c < 8; ++c) {
        if (c < 7) STAGE(c + 1, buf ^ 1);
        COMPUTE(buf, c);
        if (c == it && tid < 64) {          // fp32-exact diagonal lives in chunk `it`
            const int u = (tid >> 2) ^ (tid & 15);
            g_t[b * INn + i0 + tid] = As[buf][tid][u * 4 + (tid & 3)];
        }
        __syncthreads();                    // drains vmcnt(0): next buf staged
        buf ^= 1;
    }

    // ---- staged epilogue (identical to round 5): frags -> LDS -> 1KB stores ----
    __bf16* Uo = (__bf16*)smem;              // 16 i-groups x 384 p x 4 = 48KB
#pragma unroll
    for (int mi = 0; mi < 4; ++mi) {
        const int i4l = mi * 4 + quad;       // local i-group 0..15
#pragma unroll
        for (int nf = 0; nf < 3; ++nf) {
            const int p = p_base + nf * 16 + l15;
            bf16x4 v;
            v[0] = (__bf16)acc[mi][nf][0];
            v[1] = (__bf16)acc[mi][nf][1];
            v[2] = (__bf16)acc[mi][nf][2];
            v[3] = (__bf16)acc[mi][nf][3];
            *(bf16x4*)&Uo[(i4l * OUTn + p) * 4] = v;
        }
    }
    __syncthreads();
    {   // block's U region is contiguous: start elem = (b*128 + it*16)*1536
        char* dst = (char*)(g_U + (size_t)(b * 128 + it * 16) * 1536);
#pragma unroll
        for (int r = 0; r < 6; ++r) {
            const int L = r * 8192 + tid * 16;   // byte offset, 6*8192 = 49152
            *(bf16x8*)(dst + L) = *(const bf16x8*)(smem + L);
        }
    }
}

// ---------------------------------------------------------------------------
// k2: mu_f[b,o] = mu[b,:]·W[o,:] + bias[o]
//     d[b,o]   = sum_i (diag_sigma[b,i] + mu[b,i]^2) * sp[o,i] + (o==b)*sbias[o]
// ---------------------------------------------------------------------------
__global__ __launch_bounds__(384) void k2_kernel(const float* __restrict__ mu,
                                                 const float* __restrict__ bias,
                                                 const float* __restrict__ sbias,
                                                 float* __restrict__ out_muf) {
    const int b = blockIdx.x;
    const int t = threadIdx.x;   // = o
    __shared__ __align__(16) float muL[INn];
    __shared__ __align__(16) float tL[INn];
    for (int i = t; i < INn; i += 384) {
        float m = mu[b * INn + i];
        muL[i] = m;
        tL[i] = g_t[b * INn + i] + m * m;
    }
    __syncthreads();
    float mf = 0.f, dd = 0.f;
#pragma unroll 8
    for (int i = 0; i < INn; ++i) {
        mf += g_Wt[i * OUTn + t] * muL[i];
        dd += g_spt[i * OUTn + t] * tL[i];
    }
    out_muf[b * OUTn + t] = mf + bias[t];
    g_d[b * OUTn + t] = dd + (t == b ? sbias[t] : 0.f);
}

// ---------------------------------------------------------------------------
// passB: out[b,o,p0+p] = sum_i W[o,i] * U[b,p0+p,i]  (+ d[b,o] if o==p)
// grid (6 p-tiles of 64, 384 b), 512 thr = 8 waves. Barrier-free main loop;
// fp32 out staged through 48KB LDS in two o-halves (round-5, verified).
// ---------------------------------------------------------------------------
__global__ __launch_bounds__(512, 4) void passB_kernel(float* __restrict__ outS) {
    __shared__ __align__(16) float Os[192 * 64];   // 48KB: 192 o-rows x 64 p

    const int ptile = blockIdx.x;   // 0..5
    const int b     = blockIdx.y;   // 0..383
    const int tid   = threadIdx.x;
    const int wave  = tid >> 6, lane = tid & 63;
    const int quad  = lane >> 4, l15 = lane & 15;
    const int p0     = ptile * 64;

    const __bf16* Ub = g_U + (size_t)b * (OUTn * INn);

    f32x4 acc[3][4];
#pragma unroll
    for (int mi = 0; mi < 3; ++mi)
#pragma unroll
        for (int nf = 0; nf < 4; ++nf) acc[mi][nf] = (f32x4){0.f, 0.f, 0.f, 0.f};

    for (int kc = 0; kc < INn; kc += 32) {
        bf16x8 afr[3];
#pragma unroll
        for (int mi = 0; mi < 3; ++mi) {
            const int ot = wave * 3 + mi;
            const __bf16* ap = g_Wf + ((((size_t)(ot * 16 + (kc >> 5)) * 4 + quad) * 16 + l15) << 3);
            afr[mi] = *(const bf16x8*)ap;
        }
        const int i4 = (kc >> 2) + quad * 2;
#pragma unroll
        for (int nf = 0; nf < 4; ++nf) {
            const int p = p0 + nf * 16 + l15;
            bf16x4 lo = *(const bf16x4*)(Ub + ((size_t)i4 * OUTn + p) * 4);
            bf16x4 hi = *(const bf16x4*)(Ub + ((size_t)(i4 + 1) * OUTn + p) * 4);
            bf16x8 bfr;
            bfr[0]=lo[0]; bfr[1]=lo[1]; bfr[2]=lo[2]; bfr[3]=lo[3];
            bfr[4]=hi[0]; bfr[5]=hi[1]; bfr[6]=hi[2]; bfr[7]=hi[3];
#pragma unroll
            for (int mi = 0; mi < 3; ++mi)
                acc[mi][nf] = __builtin_amdgcn_mfma_f32_16x16x32_bf16(afr[mi], bfr, acc[mi][nf], 0, 0, 0);
        }
    }

    // ---- staged epilogue: two o-halves of 192 rows through 48KB LDS ----
    float* outb = outS + (size_t)b * (OUTn * OUTn);
    const int halfId = wave >> 2;   // waves 0-3 own o 0..191, waves 4-7 own 192..383
#pragma unroll
    for (int h = 0; h < 2; ++h) {
        if (h) __syncthreads();     // protect Os from previous half's copy
        if (halfId == h) {
#pragma unroll
            for (int mi = 0; mi < 3; ++mi) {
                const int o_loc = (wave & 3) * 48 + mi * 16 + quad * 4;
#pragma unroll
                for (int nf = 0; nf < 4; ++nf) {
                    const int p_loc = nf * 16 + l15;
                    const int p = p0 + p_loc;
#pragma unroll
                    for (int r = 0; r < 4; ++r) {
                        const int o = h * 192 + o_loc + r;
                        float v = acc[mi][nf][r];
                        if (o == p) v += g_d[b * OUTn + o];
                        Os[(o_loc + r) * 64 + p_loc] = v;
                    }
                }
            }
        }
        __syncthreads();
        // copy 48KB: each instr = 16 lanes x 16B covering one 256B o-row
#pragma unroll
        for (int r = 0; r < 6; ++r) {
            const int L     = r * 8192 + tid * 16;   // byte offset in Os
            const int o_loc = L >> 8;                // 256B per o-row
            const int pb    = L & 255;
            *(f32x4*)((char*)outb + (size_t)(h * 192 + o_loc) * (OUTn * 4) + p0 * 4 + pb) =
                *(const f32x4*)((const char*)Os + L);
        }
    }
}

// ---------------------------------------------------------------------------
extern "C" void kernel_launch(void* const* d_in, const int* in_sizes, int n_in,
                              void* d_out, int out_size, void* d_ws, size_t ws_size,
                              hipStream_t stream) {
    const float* mu    = (const float*)d_in[0];
    const float* sigma = (const float*)d_in[1];
    const float* W     = (const float*)d_in[2];
    const float* bias  = (const float*)d_in[3];
    const float* sw    = (const float*)d_in[4];
    const float* sbias = (const float*)d_in[5];

    float* out     = (float*)d_out;
    float* out_muf = out;                  // [384, 384]
    float* out_sig = out + Bn * OUTn;      // [384, 384, 384]

    prep_kernel<<<(OUTn * INn + 255) / 256, 256, 0, stream>>>(W, sw);
    passA_kernel<<<dim3(8, Bn), 512, 0, stream>>>(sigma);                    // g_U, g_t
    k2_kernel<<<Bn, 384, 0, stream>>>(mu, bias, sbias, out_muf);             // g_d
    passB_kernel<<<dim3(6, Bn), 512, 0, stream>>>(out_sig);
}